// Round 1
// baseline (269.988 us; speedup 1.0000x reference)
//
#include <hip/hip_runtime.h>

typedef _Float16 half8 __attribute__((ext_vector_type(8)));
typedef float f32x4 __attribute__((ext_vector_type(4)));

#define B_ 256
#define K_ 512
#define D_ 256
#define H_ 256
#define NROWS (B_*K_)          // 131072
#define LNEPS 1e-5f
#define ITERS 16               // row-tiles of 32 per block pair
#define INV1024 (1.0f/1024.0f)

// LDS A layout: per 32-row tile, arrays h and l; row stride 528 B (33x16,
// bank shift 4/row); chunk c (16B, k-range [8c,8c+8)) lives at byte offset
// pos(c)*16 where pos(c) = (c>>1) + 16*(c&1). Writes (seg-major) and reads
// (n16-major) both land on 8 distinct banks per 8-lane group.
#define ROWS_ 528
#define ASZ (32*ROWS_)          // 16896 per array
#define BUFSZ (2*ASZ)           // h + l = 33792 per buffer
#define LDS_BYTES (2*BUFSZ + 2048)   // 69632 -> 2 blocks/CU

__global__ __launch_bounds__(512, 4) void mfma_main(
    const float* __restrict__ slots, const float* __restrict__ gamma,
    const float* __restrict__ beta,  const float* __restrict__ w1,
    const float* __restrict__ b1,    const float* __restrict__ w2,
    float* __restrict__ ws)
{
    extern __shared__ __align__(16) char smem[];
    float2* red = (float2*)(smem + 2*BUFSZ);     // [8][32]

    const int t    = threadIdx.x;
    const int lane = t & 63;
    const int wv   = t >> 6;        // 0..7
    const int quad = lane >> 4;     // 0..3
    const int n16  = lane & 15;
    const int srow = t >> 4;        // 0..31 staging row
    const int seg  = t & 15;        // 16 d's per staging thread

    const int half_ = blockIdx.x & 1;
    const int pair  = blockIdx.x >> 1;          // == batch row
    const int colB  = half_*128 + wv*16 + n16;  // B-frag load column
    const int tile0 = pair * ITERS;

    // ---- persistent B fragments (gamma folded) + b1' = b1 + beta.W1 ----
    half8 Bh[8], Bl[8];
    float bsum = 0.f;
    #pragma unroll
    for (int ks = 0; ks < 8; ++ks) {
        const int k0 = ks*32 + quad*8;
        half8 h, l;
        #pragma unroll
        for (int j = 0; j < 8; ++j) {
            const float w  = w1[(size_t)(k0 + j)*H_ + colB];
            bsum += beta[k0 + j] * w;
            const float wg = gamma[k0 + j] * w;
            const _Float16 hh = (_Float16)wg;
            h[j] = hh;
            l[j] = (_Float16)((wg - (float)hh) * 1024.0f);
        }
        Bh[ks] = h; Bl[ks] = l;
    }
    bsum += __shfl_xor(bsum, 16, 64);
    bsum += __shfl_xor(bsum, 32, 64);
    const float b1col = b1[colB] + bsum;   // valid for col colB (lane n16)

    // redistribute epilogue constants to D layout: col = base + quad*4 + reg
    float b1p[4], w20[4], w21[4];
    #pragma unroll
    for (int reg = 0; reg < 4; ++reg) {
        const int cq = quad*4 + reg;                    // 0..15
        b1p[reg] = __shfl(b1col, cq, 64);               // from lane cq
        const int col = half_*128 + wv*16 + cq;
        w20[reg] = w2[2*col + 0];
        w21[reg] = w2[2*col + 1];
    }

    // LN (xhat only) + fp16 split + permuted LDS store of one 32-row tile
    auto ln_stage = [&](const float* xr, char* buf) {
        float s = 0.f;
        #pragma unroll
        for (int j = 0; j < 16; ++j) s += xr[j];
        s += __shfl_xor(s, 1, 64); s += __shfl_xor(s, 2, 64);
        s += __shfl_xor(s, 4, 64); s += __shfl_xor(s, 8, 64);
        const float mean = s * (1.f/256.f);
        float q = 0.f;
        #pragma unroll
        for (int j = 0; j < 16; ++j) { const float d = xr[j]-mean; q += d*d; }
        q += __shfl_xor(q, 1, 64); q += __shfl_xor(q, 2, 64);
        q += __shfl_xor(q, 4, 64); q += __shfl_xor(q, 8, 64);
        const float rstd = rsqrtf(q * (1.f/256.f) + LNEPS);
        char* hrow = buf        + srow*ROWS_;
        char* lrow = buf + ASZ  + srow*ROWS_;
        #pragma unroll
        for (int b = 0; b < 2; ++b) {        // chunk c = 2*seg+b, pos = seg + 16*b
            half8 hh, ll;
            #pragma unroll
            for (int jj = 0; jj < 8; ++jj) {
                const float x = (xr[b*8 + jj] - mean) * rstd;
                const _Float16 xh = (_Float16)x;
                hh[jj] = xh;
                ll[jj] = (_Float16)((x - (float)xh) * 1024.0f);
            }
            const int off = (seg + 16*b) * 16;
            *(half8*)(hrow + off) = hh;
            *(half8*)(lrow + off) = ll;
        }
    };

    // prologue: stage tile0 into buffer 0
    {
        const float* sp = slots + ((size_t)tile0*32 + srow)*D_ + seg*16;
        float xr[16];
        #pragma unroll
        for (int i4 = 0; i4 < 4; ++i4) {
            const float4 v = ((const float4*)sp)[i4];
            xr[4*i4+0]=v.x; xr[4*i4+1]=v.y; xr[4*i4+2]=v.z; xr[4*i4+3]=v.w;
        }
        ln_stage(xr, smem);
    }
    __syncthreads();

    for (int i = 0; i < ITERS; ++i) {
        const int p = i & 1;
        const bool have_next = (i + 1 < ITERS);

        // prefetch next tile (global latency hidden under MFMA phase)
        float xr[16];
        if (have_next) {
            const float* sp = slots + ((size_t)(tile0+i+1)*32 + srow)*D_ + seg*16;
            #pragma unroll
            for (int i4 = 0; i4 < 4; ++i4) {
                const float4 v = ((const float4*)sp)[i4];
                xr[4*i4+0]=v.x; xr[4*i4+1]=v.y; xr[4*i4+2]=v.z; xr[4*i4+3]=v.w;
            }
        }

        // ---- MFMA: 3-pass split over K=256, operands swapped:
        //      D[m=col(quad*4+reg)][n=slotrow(n16)] ----
        const char* Ah = smem + (size_t)p*BUFSZ;
        const char* Al = Ah + ASZ;
        f32x4 Ch[2], Cl[2];
        Ch[0] = (f32x4)0.f; Ch[1] = (f32x4)0.f;
        Cl[0] = (f32x4)0.f; Cl[1] = (f32x4)0.f;

        // T5: two co-resident blocks/CU run phase-shifted (one stages while
        // the other is here) -> priority arbitration has headroom to exploit.
        __builtin_amdgcn_s_setprio(1);
        #pragma unroll
        for (int ks = 0; ks < 8; ++ks) {
            const int c   = ks*4 + quad;                    // chunk index
            const int off = ((c>>1) + 16*(c&1)) * 16;       // pos(c)*16
            const half8 ah0 = *(const half8*)(Ah +  n16     *ROWS_ + off);
            const half8 ah1 = *(const half8*)(Ah + (n16+16) *ROWS_ + off);
            const half8 al0 = *(const half8*)(Al +  n16     *ROWS_ + off);
            const half8 al1 = *(const half8*)(Al + (n16+16) *ROWS_ + off);
            Ch[0] = __builtin_amdgcn_mfma_f32_16x16x32_f16(Bh[ks], ah0, Ch[0], 0,0,0);
            Ch[1] = __builtin_amdgcn_mfma_f32_16x16x32_f16(Bh[ks], ah1, Ch[1], 0,0,0);
            Cl[0] = __builtin_amdgcn_mfma_f32_16x16x32_f16(Bl[ks], ah0, Cl[0], 0,0,0);
            Cl[1] = __builtin_amdgcn_mfma_f32_16x16x32_f16(Bl[ks], ah1, Cl[1], 0,0,0);
            Cl[0] = __builtin_amdgcn_mfma_f32_16x16x32_f16(Bh[ks], al0, Cl[0], 0,0,0);
            Cl[1] = __builtin_amdgcn_mfma_f32_16x16x32_f16(Bh[ks], al1, Cl[1], 0,0,0);
        }
        __builtin_amdgcn_s_setprio(0);

        // ---- epilogue: relu + w2; reduce 4 regs in-register + 2 shfl ----
        #pragma unroll
        for (int rs = 0; rs < 2; ++rs) {
            float p0 = 0.f, p1 = 0.f;
            #pragma unroll
            for (int reg = 0; reg < 4; ++reg) {
                float hv = Ch[rs][reg] + Cl[rs][reg]*INV1024 + b1p[reg];
                hv = fmaxf(hv, 0.f);
                p0 = fmaf(hv, w20[reg], p0);
                p1 = fmaf(hv, w21[reg], p1);
            }
            p0 += __shfl_xor(p0, 16, 64); p1 += __shfl_xor(p1, 16, 64);
            p0 += __shfl_xor(p0, 32, 64); p1 += __shfl_xor(p1, 32, 64);
            if (lane < 16)                       // quad 0 holds the total
                red[wv*32 + rs*16 + n16] = make_float2(p0, p1);
        }
        __syncthreads();

        // ---- finalize: combine 8 waves -> float2 partial to ws ----
        if (t < 32) {
            float p0 = 0.f, p1 = 0.f;
            #pragma unroll
            for (int w = 0; w < 8; ++w) {
                const float2 v = red[w*32 + t];
                p0 += v.x; p1 += v.y;
            }
            const int grow = (tile0 + i)*32 + t;
            ((float2*)ws)[(size_t)half_*NROWS + grow] = make_float2(p0, p1);
        }
        // ---- stage next tile into other buffer ----
        if (have_next)
            ln_stage(xr, smem + (size_t)(p^1)*BUFSZ);
        __syncthreads();
    }
}

// Combine: one block per batch row. Sum col-half partials, gumbel decision,
// soft prob, fused lower-bound fixup (single writer per out element).
__global__ __launch_bounds__(512) void combine(
    const float* __restrict__ ws, const float* __restrict__ b2,
    const float* __restrict__ u,  const float* __restrict__ rk,
    float* __restrict__ out)
{
    __shared__ unsigned long long best[8];
    __shared__ int cnts[8];
    __shared__ int s_need, s_kbest;
    const int b = blockIdx.x;
    const int k = threadIdx.x;          // 0..511
    const int row = b*K_ + k;
    const int wv = k >> 6;

    const float2 q0 = ((const float2*)ws)[row];
    const float2 q1 = ((const float2*)ws)[NROWS + row];
    const float l0 = b2[0] + q0.x + q1.x;
    const float l1 = b2[1] + q0.y + q1.y;
    const float2 uu = ((const float2*)u)[row];
    const float g0 = -logf(-logf(uu.x));
    const float g1 = -logf(-logf(uu.y));
    const bool keep = (l1 + g1) > (l0 + g0);
    out[NROWS + row] = 1.f / (1.f + expf(l0 - l1));

    unsigned long long comb = 0;
    if (!keep)
        comb = ((unsigned long long)__float_as_uint(rk[row]) << 32)
             | (unsigned)(K_ - 1 - k);
    const int wcount = __popcll(__ballot(keep));
    #pragma unroll
    for (int off = 32; off >= 1; off >>= 1) {
        const unsigned long long o = __shfl_xor(comb, off, 64);
        if (o > comb) comb = o;
    }
    if ((k & 63) == 0) { best[wv] = comb; cnts[wv] = wcount; }
    __syncthreads();
    if (k == 0) {
        int tot = 0; unsigned long long bc = 0;
        #pragma unroll
        for (int w = 0; w < 8; ++w) { tot += cnts[w]; if (best[w] > bc) bc = best[w]; }
        s_need  = (tot == 0);
        s_kbest = (K_ - 1) - (int)(bc & 0xffffffffu);
    }
    __syncthreads();
    const bool m = keep || (s_need && (k == s_kbest));
    out[row] = m ? 1.f : 0.f;
}

extern "C" void kernel_launch(void* const* d_in, const int* in_sizes, int n_in,
                              void* d_out, int out_size, void* d_ws, size_t ws_size,
                              hipStream_t stream) {
    const float* slots = (const float*)d_in[0];
    const float* gamma = (const float*)d_in[1];
    const float* beta  = (const float*)d_in[2];
    const float* w1    = (const float*)d_in[3];
    const float* b1    = (const float*)d_in[4];
    const float* w2    = (const float*)d_in[5];
    const float* b2    = (const float*)d_in[6];
    const float* u     = (const float*)d_in[7];
    const float* rk    = (const float*)d_in[8];
    float* out = (float*)d_out;
    float* ws  = (float*)d_ws;   // 2 halves x NROWS float2 = 2 MB

    hipLaunchKernelGGL(mfma_main, dim3(512), dim3(512), LDS_BYTES, stream,
                       slots, gamma, beta, w1, b1, w2, ws);
    hipLaunchKernelGGL(combine, dim3(B_), dim3(512), 0, stream,
                       ws, b2, u, rk, out);
}

// Round 2
// 231.863 us; speedup vs baseline: 1.1644x; 1.1644x over previous
//
#include <hip/hip_runtime.h>

typedef _Float16 half8 __attribute__((ext_vector_type(8)));
typedef float f32x4 __attribute__((ext_vector_type(4)));

#define B_ 256
#define K_ 512
#define D_ 256
#define H_ 256
#define NROWS (B_*K_)          // 131072
#define LNEPS 1e-5f
#define ITERS 16               // row-tiles of 32 per block
#define INV1024 (1.0f/1024.0f)

// LDS A layout: per 32-row tile, arrays h and l; row stride 528 B (33x16,
// bank shift 4/row); chunk c (16B, k-range [8c,8c+8)) lives at byte offset
// pos(c)*16 where pos(c) = (c>>1) + 16*(c&1). Writes (one chunk per thread,
// 32 chunks/row = a permutation of 16B slots) and reads (n16-major) are
// conflict-free.
#define ROWS_ 528
#define ASZ (32*ROWS_)          // 16896 per array
#define BUFSZ (2*ASZ)           // h + l = 33792 per buffer
#define LDS_BYTES (2*BUFSZ + 4096)   // 71680 -> 1 block/CU (16 waves)

// 1024 threads = 16 waves; each wave owns 16 H-columns -> all 256 cols in
// ONE block: slots tile staged/LN'd ONCE (old block-pair did it twice).
// grid = 256 = one block per CU, zero tail.
__global__ __launch_bounds__(1024, 4) void mfma_main(
    const float* __restrict__ slots, const float* __restrict__ gamma,
    const float* __restrict__ beta,  const float* __restrict__ w1,
    const float* __restrict__ b1,    const float* __restrict__ w2,
    float* __restrict__ ws)
{
    extern __shared__ __align__(16) char smem[];
    float2* red = (float2*)(smem + 2*BUFSZ);     // [16][32]

    const int t    = threadIdx.x;
    const int lane = t & 63;
    const int wv   = t >> 6;        // 0..15
    const int quad = lane >> 4;     // 0..3
    const int n16  = lane & 15;
    const int srow = t >> 5;        // 0..31 staging row
    const int seg8 = t & 31;        // 8 d's (one chunk) per staging thread

    const int colB  = wv*16 + n16;  // B-frag load column (0..255)
    const int tile0 = blockIdx.x * ITERS;

    // ---- persistent B fragments (gamma folded) + b1' = b1 + beta.W1 ----
    half8 Bh[8], Bl[8];
    float bsum = 0.f;
    #pragma unroll
    for (int ks = 0; ks < 8; ++ks) {
        const int k0 = ks*32 + quad*8;
        half8 h, l;
        #pragma unroll
        for (int j = 0; j < 8; ++j) {
            const float w  = w1[(size_t)(k0 + j)*H_ + colB];
            bsum += beta[k0 + j] * w;
            const float wg = gamma[k0 + j] * w;
            const _Float16 hh = (_Float16)wg;
            h[j] = hh;
            l[j] = (_Float16)((wg - (float)hh) * 1024.0f);
        }
        Bh[ks] = h; Bl[ks] = l;
    }
    bsum += __shfl_xor(bsum, 16, 64);
    bsum += __shfl_xor(bsum, 32, 64);
    const float b1col = b1[colB] + bsum;   // valid for col colB (lane n16)

    // redistribute epilogue constants to D layout: col = base + quad*4 + reg
    float b1p[4], w20[4], w21[4];
    #pragma unroll
    for (int reg = 0; reg < 4; ++reg) {
        const int cq = quad*4 + reg;                    // 0..15
        b1p[reg] = __shfl(b1col, cq, 64);               // from lane cq
        const int col = wv*16 + cq;
        w20[reg] = w2[2*col + 0];
        w21[reg] = w2[2*col + 1];
    }

    // LN (xhat only) + fp16 split + permuted LDS store of one 32-row tile.
    // Each thread owns 8 d's (chunk c = seg8); row split over 32 lanes.
    auto ln_stage = [&](const float* xr, char* buf) {
        float s = 0.f;
        #pragma unroll
        for (int j = 0; j < 8; ++j) s += xr[j];
        s += __shfl_xor(s, 1, 64); s += __shfl_xor(s, 2, 64);
        s += __shfl_xor(s, 4, 64); s += __shfl_xor(s, 8, 64);
        s += __shfl_xor(s, 16, 64);
        const float mean = s * (1.f/256.f);
        float q = 0.f;
        #pragma unroll
        for (int j = 0; j < 8; ++j) { const float d = xr[j]-mean; q += d*d; }
        q += __shfl_xor(q, 1, 64); q += __shfl_xor(q, 2, 64);
        q += __shfl_xor(q, 4, 64); q += __shfl_xor(q, 8, 64);
        q += __shfl_xor(q, 16, 64);
        const float rstd = rsqrtf(q * (1.f/256.f) + LNEPS);
        half8 hh, ll;
        #pragma unroll
        for (int jj = 0; jj < 8; ++jj) {
            const float x = (xr[jj] - mean) * rstd;
            const _Float16 xh = (_Float16)x;
            hh[jj] = xh;
            ll[jj] = (_Float16)((x - (float)xh) * 1024.0f);
        }
        const int off = srow*ROWS_ + ((seg8>>1) + 16*(seg8&1)) * 16;
        *(half8*)(buf + off)       = hh;
        *(half8*)(buf + ASZ + off) = ll;
    };

    // prologue: stage tile0 into buffer 0
    {
        const float* sp = slots + ((size_t)tile0*32 + srow)*D_ + seg8*8;
        float xr[8];
        #pragma unroll
        for (int i4 = 0; i4 < 2; ++i4) {
            const float4 v = ((const float4*)sp)[i4];
            xr[4*i4+0]=v.x; xr[4*i4+1]=v.y; xr[4*i4+2]=v.z; xr[4*i4+3]=v.w;
        }
        ln_stage(xr, smem);
    }
    __syncthreads();

    for (int i = 0; i < ITERS; ++i) {
        const int p = i & 1;
        const bool have_next = (i + 1 < ITERS);

        // prefetch next tile (global latency hidden under MFMA phase)
        float xr[8];
        if (have_next) {
            const float* sp = slots + ((size_t)(tile0+i+1)*32 + srow)*D_ + seg8*8;
            #pragma unroll
            for (int i4 = 0; i4 < 2; ++i4) {
                const float4 v = ((const float4*)sp)[i4];
                xr[4*i4+0]=v.x; xr[4*i4+1]=v.y; xr[4*i4+2]=v.z; xr[4*i4+3]=v.w;
            }
        }

        // ---- MFMA: 3-pass split over K=256, operands swapped:
        //      D[m=col(quad*4+reg)][n=slotrow(n16)] ----
        const char* Ah = smem + (size_t)p*BUFSZ;
        const char* Al = Ah + ASZ;
        f32x4 Ch[2], Cl[2];
        Ch[0] = (f32x4)0.f; Ch[1] = (f32x4)0.f;
        Cl[0] = (f32x4)0.f; Cl[1] = (f32x4)0.f;

        #pragma unroll
        for (int ks = 0; ks < 8; ++ks) {
            const int c   = ks*4 + quad;                    // chunk index
            const int off = ((c>>1) + 16*(c&1)) * 16;       // pos(c)*16
            const half8 ah0 = *(const half8*)(Ah +  n16     *ROWS_ + off);
            const half8 ah1 = *(const half8*)(Ah + (n16+16) *ROWS_ + off);
            const half8 al0 = *(const half8*)(Al +  n16     *ROWS_ + off);
            const half8 al1 = *(const half8*)(Al + (n16+16) *ROWS_ + off);
            Ch[0] = __builtin_amdgcn_mfma_f32_16x16x32_f16(Bh[ks], ah0, Ch[0], 0,0,0);
            Ch[1] = __builtin_amdgcn_mfma_f32_16x16x32_f16(Bh[ks], ah1, Ch[1], 0,0,0);
            Cl[0] = __builtin_amdgcn_mfma_f32_16x16x32_f16(Bl[ks], ah0, Cl[0], 0,0,0);
            Cl[1] = __builtin_amdgcn_mfma_f32_16x16x32_f16(Bl[ks], ah1, Cl[1], 0,0,0);
            Cl[0] = __builtin_amdgcn_mfma_f32_16x16x32_f16(Bh[ks], al0, Cl[0], 0,0,0);
            Cl[1] = __builtin_amdgcn_mfma_f32_16x16x32_f16(Bh[ks], al1, Cl[1], 0,0,0);
        }

        // ---- epilogue: relu + w2; reduce 4 regs in-register + 2 shfl ----
        #pragma unroll
        for (int rs = 0; rs < 2; ++rs) {
            float p0 = 0.f, p1 = 0.f;
            #pragma unroll
            for (int reg = 0; reg < 4; ++reg) {
                float hv = Ch[rs][reg] + Cl[rs][reg]*INV1024 + b1p[reg];
                hv = fmaxf(hv, 0.f);
                p0 = fmaf(hv, w20[reg], p0);
                p1 = fmaf(hv, w21[reg], p1);
            }
            p0 += __shfl_xor(p0, 16, 64); p1 += __shfl_xor(p1, 16, 64);
            p0 += __shfl_xor(p0, 32, 64); p1 += __shfl_xor(p1, 32, 64);
            if (lane < 16)                       // quad 0 holds the total
                red[wv*32 + rs*16 + n16] = make_float2(p0, p1);
        }
        __syncthreads();

        // ---- finalize: combine 16 waves -> float2 logits-partial to ws ----
        if (t < 32) {
            float p0 = 0.f, p1 = 0.f;
            #pragma unroll
            for (int w = 0; w < 16; ++w) {
                const float2 v = red[w*32 + t];
                p0 += v.x; p1 += v.y;
            }
            const int grow = (tile0 + i)*32 + t;
            ((float2*)ws)[grow] = make_float2(p0, p1);
        }
        // ---- stage next tile into other buffer ----
        if (have_next)
            ln_stage(xr, smem + (size_t)(p^1)*BUFSZ);
        __syncthreads();
    }
}

// Combine: one block per batch row. Gumbel decision, soft prob, fused
// lower-bound fixup (single writer per out element).
__global__ __launch_bounds__(512) void combine(
    const float* __restrict__ ws, const float* __restrict__ b2,
    const float* __restrict__ u,  const float* __restrict__ rk,
    float* __restrict__ out)
{
    __shared__ unsigned long long best[8];
    __shared__ int cnts[8];
    __shared__ int s_need, s_kbest;
    const int b = blockIdx.x;
    const int k = threadIdx.x;          // 0..511
    const int row = b*K_ + k;
    const int wv = k >> 6;

    const float2 q0 = ((const float2*)ws)[row];
    const float l0 = b2[0] + q0.x;
    const float l1 = b2[1] + q0.y;
    const float2 uu = ((const float2*)u)[row];
    const float g0 = -logf(-logf(uu.x));
    const float g1 = -logf(-logf(uu.y));
    const bool keep = (l1 + g1) > (l0 + g0);
    out[NROWS + row] = 1.f / (1.f + expf(l0 - l1));

    unsigned long long comb = 0;
    if (!keep)
        comb = ((unsigned long long)__float_as_uint(rk[row]) << 32)
             | (unsigned)(K_ - 1 - k);
    const int wcount = __popcll(__ballot(keep));
    #pragma unroll
    for (int off = 32; off >= 1; off >>= 1) {
        const unsigned long long o = __shfl_xor(comb, off, 64);
        if (o > comb) comb = o;
    }
    if ((k & 63) == 0) { best[wv] = comb; cnts[wv] = wcount; }
    __syncthreads();
    if (k == 0) {
        int tot = 0; unsigned long long bc = 0;
        #pragma unroll
        for (int w = 0; w < 8; ++w) { tot += cnts[w]; if (best[w] > bc) bc = best[w]; }
        s_need  = (tot == 0);
        s_kbest = (K_ - 1) - (int)(bc & 0xffffffffu);
    }
    __syncthreads();
    const bool m = keep || (s_need && (k == s_kbest));
    out[row] = m ? 1.f : 0.f;
}

extern "C" void kernel_launch(void* const* d_in, const int* in_sizes, int n_in,
                              void* d_out, int out_size, void* d_ws, size_t ws_size,
                              hipStream_t stream) {
    const float* slots = (const float*)d_in[0];
    const float* gamma = (const float*)d_in[1];
    const float* beta  = (const float*)d_in[2];
    const float* w1    = (const float*)d_in[3];
    const float* b1    = (const float*)d_in[4];
    const float* w2    = (const float*)d_in[5];
    const float* b2    = (const float*)d_in[6];
    const float* u     = (const float*)d_in[7];
    const float* rk    = (const float*)d_in[8];
    float* out = (float*)d_out;
    float* ws  = (float*)d_ws;   // NROWS float2 = 1 MB

    hipLaunchKernelGGL(mfma_main, dim3(B_), dim3(1024), LDS_BYTES, stream,
                       slots, gamma, beta, w1, b1, w2, ws);
    hipLaunchKernelGGL(combine, dim3(B_), dim3(512), 0, stream,
                       ws, b2, u, rk, out);
}